// Round 1
// baseline (273.045 us; speedup 1.0000x reference)
//
#include <hip/hip_runtime.h>

// BaseEncoder: x[B,F] fp32 -> out[B,F,32] fp32
//   out[...,0]    = (x < 0) ? 1 : 0
//   out[...,1+d]  = bit (30-d) of bitcast(|x|), d = 0..30  (MSB-first)
//
// Layout: 8 threads per input element, each thread produces 4 consecutive
// output channels and does ONE float4 store -> consecutive lanes write
// consecutive 16B (perfect coalescing, 1 KiB per wave store instr).
// For j>=1 the selected bit positions are 0..30, which never include the
// IEEE sign bit, so the raw bitcast needs no abs-masking; j==0 uses the
// exact (x<0) compare (handles -0.0 like the reference).

__global__ __launch_bounds__(256) void base_encoder_kernel(
    const float* __restrict__ x, float4* __restrict__ out, int n_quads) {
  int tid = blockIdx.x * blockDim.x + threadIdx.x;
  if (tid >= n_quads) return;

  int elem = tid >> 3;   // input element index
  int quad = tid & 7;    // which group of 4 output channels
  float xv = x[elem];
  unsigned r = __float_as_uint(xv);
  int j0 = quad << 2;    // base output channel index (0,4,...,28)

  float v[4];
#pragma unroll
  for (int t = 0; t < 4; ++t) {
    int j = j0 + t;                       // output channel 0..31
    unsigned bit = (r >> (31 - j)) & 1u;  // j>=1: mantissa/exponent bits only
    v[t] = (float)bit;
  }
  // channel 0: sign channel via exact compare (not the raw sign bit)
  if (j0 == 0) v[0] = (xv < 0.0f) ? 1.0f : 0.0f;

  float4 o;
  o.x = v[0]; o.y = v[1]; o.z = v[2]; o.w = v[3];
  out[tid] = o;
}

extern "C" void kernel_launch(void* const* d_in, const int* in_sizes, int n_in,
                              void* d_out, int out_size, void* d_ws, size_t ws_size,
                              hipStream_t stream) {
  const float* x = (const float*)d_in[0];
  float4* out = (float4*)d_out;
  int n_elems = in_sizes[0];        // 4096*512 = 2,097,152
  int n_quads = n_elems * 8;        // one float4 per thread; == out_size/4
  const int block = 256;
  int grid = (n_quads + block - 1) / block;
  base_encoder_kernel<<<grid, block, 0, stream>>>(x, out, n_quads);
}